// Round 2
// baseline (148.240 us; speedup 1.0000x reference)
//
#include <hip/hip_runtime.h>
#include <hip/hip_bf16.h>
#include <math.h>

typedef __bf16 bf16_t;
typedef __bf16 bf16x2 __attribute__((ext_vector_type(2)));
typedef __bf16 bf16x4 __attribute__((ext_vector_type(4)));
typedef __bf16 bf16x8 __attribute__((ext_vector_type(8)));
typedef float floatx4 __attribute__((ext_vector_type(4)));

constexpr int N_ = 4, L_ = 2048, S_ = 2048, H_ = 8, D_ = 64;

// async global->LDS, 16B/lane; LDS dest = wave-uniform base + lane*16
__device__ __forceinline__ void async_load16(const void* g, void* l) {
  __builtin_amdgcn_global_load_lds(
      (const __attribute__((address_space(1))) void*)g,
      (__attribute__((address_space(3))) void*)l, 16, 0, 0);
}

// ---------------------------------------------------------------------------
// prologue: K fp32 [n,s,h,d] -> bf16 Kb [nh,s,d]; V fp32 -> bf16 Vtb [nh,d,s]
__global__ __launch_bounds__(256)
void prep(const float* __restrict__ Kg, const float* __restrict__ Vg,
          bf16_t* __restrict__ Kb, bf16_t* __restrict__ Vtb) {
  __shared__ bf16x2 pr_sh[64 * 33];
  const int tid = threadIdx.x;
  const int nh = blockIdx.y, s0 = blockIdx.x * 64;
  const int n = nh >> 3, h = nh & 7;
  {
    const int srow = tid >> 2, d0 = (tid & 3) * 16;
    const float* kp = Kg + (((size_t)n * S_ + s0 + srow) * H_ + h) * D_ + d0;
    float4 x0 = ((const float4*)kp)[0], x1 = ((const float4*)kp)[1];
    float4 x2 = ((const float4*)kp)[2], x3 = ((const float4*)kp)[3];
    bf16x8 f0, f1;
    f0[0] = (bf16_t)x0.x; f0[1] = (bf16_t)x0.y; f0[2] = (bf16_t)x0.z; f0[3] = (bf16_t)x0.w;
    f0[4] = (bf16_t)x1.x; f0[5] = (bf16_t)x1.y; f0[6] = (bf16_t)x1.z; f0[7] = (bf16_t)x1.w;
    f1[0] = (bf16_t)x2.x; f1[1] = (bf16_t)x2.y; f1[2] = (bf16_t)x2.z; f1[3] = (bf16_t)x2.w;
    f1[4] = (bf16_t)x3.x; f1[5] = (bf16_t)x3.y; f1[6] = (bf16_t)x3.z; f1[7] = (bf16_t)x3.w;
    *(bf16x8*)&Kb[((size_t)nh * S_ + s0 + srow) * D_ + d0] = f0;
    *(bf16x8*)&Kb[((size_t)nh * S_ + s0 + srow) * D_ + d0 + 8] = f1;
  }
  {
    const int s2 = tid >> 3;
    const int dg = (tid & 7) * 8;
    const float* vp0 = Vg + (((size_t)n * S_ + s0 + 2 * s2) * H_ + h) * D_ + dg;
    const float* vp1 = vp0 + (size_t)H_ * D_;
    float4 a0 = ((const float4*)vp0)[0], a1 = ((const float4*)vp0)[1];
    float4 b0 = ((const float4*)vp1)[0], b1 = ((const float4*)vp1)[1];
    float r0[8] = { a0.x, a0.y, a0.z, a0.w, a1.x, a1.y, a1.z, a1.w };
    float r1[8] = { b0.x, b0.y, b0.z, b0.w, b1.x, b1.y, b1.z, b1.w };
#pragma unroll
    for (int j = 0; j < 8; ++j) {
      bf16x2 pr; pr[0] = (bf16_t)r0[j]; pr[1] = (bf16_t)r1[j];
      pr_sh[(dg + j) * 33 + s2] = pr;
    }
  }
  __syncthreads();
  {
    const int dr = tid >> 2, sq = tid & 3;
    bf16x8 o0, o1;
#pragma unroll
    for (int p = 0; p < 4; ++p) {
      bf16x2 v = pr_sh[dr * 33 + sq * 8 + p];
      o0[2 * p] = v[0]; o0[2 * p + 1] = v[1];
    }
#pragma unroll
    for (int p = 0; p < 4; ++p) {
      bf16x2 v = pr_sh[dr * 33 + sq * 8 + 4 + p];
      o1[2 * p] = v[0]; o1[2 * p + 1] = v[1];
    }
    bf16_t* op = &Vtb[((size_t)nh * D_ + dr) * S_ + s0 + sq * 16];
    *(bf16x8*)op = o0;
    *(bf16x8*)(op + 8) = o1;
  }
}

// ---------------------------------------------------------------------------
// fattn r11: occupancy rewrite. Wave = (q-half, s-half): 32q x 64d tile,
// 1024 s in 32 chunks of 32. oacc 32 regs + qf 16 -> fits 128-reg cap ->
// __launch_bounds__(256,4): 4 blocks/CU (16 waves/CU), ALL 1024 blocks
// resident, single round. P never touches LDS: swapped-QK output is packed
// with v_cvt_pk_bf16_f32 and redistributed to PV A-frags with
// permlane32_swap+permlane16_swap (both-results builtins). PV runs
// in-iteration (no carry). K/V single-buffered 8KB/wave; r7/r8 race
// discipline: vmcnt(0) at top, lgkmcnt(0) before DMA reissue.
__global__ __launch_bounds__(256, 4)
void fattn(const float* __restrict__ Qg, const bf16_t* __restrict__ Kb,
           const bf16_t* __restrict__ Vtb, float* __restrict__ Og) {
  __shared__ __align__(16) char smem[35328];  // loop: 32KB; epi: 34816+512

  const int tid  = threadIdx.x;
  const int wave = tid >> 6;
  const int lane = tid & 63;
  const int quad = lane >> 4;
  const int l16  = lane & 15;
  const int qh   = wave >> 1;  // q-half (32 rows)
  const int sh   = wave & 1;   // s-half (1024 cols)
  char* wbase = smem + wave * 8192;
  bf16_t* kbuf = (bf16_t*)(wbase);
  bf16_t* vbuf = (bf16_t*)(wbase + 4096);

  // XCD swizzle: nh from low 5 bits -> each nh's 1MB K/V pinned to one XCD L2
  const int lb = blockIdx.x;
  const int nh = (lb & 7) * 4 + ((lb >> 3) & 3);
  const int qb = lb >> 5;
  const int n  = nh >> 3;
  const int h  = nh & 7;
  const int l0 = qb * 64;

  // ---- Q B-frags (B[k=d][n=q]: n=l16, k=quad*8+j), scale*log2e folded ----
  const float qs = 0.125f * 1.44269504088896340736f;
  bf16x8 qf[2][2];
#pragma unroll
  for (int nbq = 0; nbq < 2; ++nbq) {
    const int q = l0 + qh * 32 + nbq * 16 + l16;
    const float* qp = Qg + (((size_t)n * L_ + q) * H_ + h) * D_;
#pragma unroll
    for (int kc = 0; kc < 2; ++kc) {
      const float* p = qp + kc * 32 + quad * 8;
      float4 a = ((const float4*)p)[0];
      float4 b = ((const float4*)p)[1];
      bf16x8 f;
      f[0] = (bf16_t)(a.x * qs); f[1] = (bf16_t)(a.y * qs);
      f[2] = (bf16_t)(a.z * qs); f[3] = (bf16_t)(a.w * qs);
      f[4] = (bf16_t)(b.x * qs); f[5] = (bf16_t)(b.y * qs);
      f[6] = (bf16_t)(b.z * qs); f[7] = (bf16_t)(b.w * qs);
      qf[nbq][kc] = f;
    }
  }

  floatx4 oacc[2][4];
#pragma unroll
  for (int a = 0; a < 2; ++a)
#pragma unroll
    for (int b = 0; b < 4; ++b) oacc[a][b] = (floatx4){0.f, 0.f, 0.f, 0.f};
  float lsum_p[2] = {0.f, 0.f};

  const bf16_t* kbase = Kb + (size_t)nh * S_ * D_;
  const bf16_t* vbase = Vtb + (size_t)nh * D_ * S_;

  // DMA lane constants (XOR-swizzled 16B chunks, verified round 6)
  const int krr  = lane >> 3;
  const int kcol = ((lane & 7) ^ ((lane >> 3) & 7)) * 8;
  const int vrr  = lane >> 2;
  const int vcol = ((lane & 3) ^ ((lane >> 3) & 3)) * 8;

  const int sbase = sh * 1024;

  // prime t=0
  {
    const int s0w = sbase;
#pragma unroll
    for (int i = 0; i < 4; ++i)
      async_load16(kbase + (size_t)(s0w + i * 8 + krr) * 64 + kcol,
                   (char*)kbuf + i * 1024);
#pragma unroll
    for (int i = 0; i < 4; ++i)
      async_load16(vbase + (size_t)(i * 16 + vrr) * S_ + s0w + vcol,
                   (char*)vbuf + i * 1024);
  }

  for (int t = 0; t < 32; ++t) {
    // this iter's 8 DMA loads (the only vmem in flight)
    asm volatile("s_waitcnt vmcnt(0)" ::: "memory");

    // K A-frags (A[m=s: l16][k=d: quad*8+j]), swizzle key l16&7
    bf16x8 ka[2][2];
#pragma unroll
    for (int mb = 0; mb < 2; ++mb)
#pragma unroll
      for (int kc = 0; kc < 2; ++kc)
        ka[mb][kc] = *(const bf16x8*)
            &kbuf[(mb * 16 + l16) * 64 + (((kc * 4 + quad) ^ (l16 & 7)) * 8)];

    // V B-frags (B[k=s: quad*8+j][n=d: l16]), swizzle key (row>>1)&3
    bf16x8 vb[4];
#pragma unroll
    for (int nbd = 0; nbd < 4; ++nbd) {
      const int row = nbd * 16 + l16;
      vb[nbd] = *(const bf16x8*)
          &vbuf[row * 32 + ((quad ^ ((row >> 1) & 3)) * 8)];
    }

    // drain LDS pipe: ka/vb in registers before DMA can overwrite buffers
    asm volatile("s_waitcnt lgkmcnt(0)" ::: "memory");

    // issue DMA for t+1 into the SAME buffers (safe after the fence)
    if (t < 31) {
      const int s0n = sbase + (t + 1) * 32;
#pragma unroll
      for (int i = 0; i < 4; ++i)
        async_load16(kbase + (size_t)(s0n + i * 8 + krr) * 64 + kcol,
                     (char*)kbuf + i * 1024);
#pragma unroll
      for (int i = 0; i < 4; ++i)
        async_load16(vbase + (size_t)(i * 16 + vrr) * S_ + s0n + vcol,
                     (char*)vbuf + i * 1024);
    }

    // ---- S^T(t) = K Q^T: contiguous MFMA cluster ----
    floatx4 sacc[2][2];
    __builtin_amdgcn_s_setprio(1);
#pragma unroll
    for (int nbq = 0; nbq < 2; ++nbq)
#pragma unroll
      for (int mb = 0; mb < 2; ++mb) {
        floatx4 acc = (floatx4){0.f, 0.f, 0.f, 0.f};
        acc = __builtin_amdgcn_mfma_f32_16x16x32_bf16(ka[mb][0], qf[nbq][0], acc, 0, 0, 0);
        acc = __builtin_amdgcn_mfma_f32_16x16x32_bf16(ka[mb][1], qf[nbq][1], acc, 0, 0, 0);
        sacc[nbq][mb] = acc;
      }
    __builtin_amdgcn_s_setprio(0);

    // ---- exp2 + cvt_pk + permlane redistribution -> PV A-frags ----
    // Lane(l16,quad) holds P[q=nbq*16+l16][s=mb*16+quad*4+r]. PV A-frag
    // needs lane(l16,qd) to hold s=qd*8..qd*8+7. With R=w[0][h], T=w[1][h]:
    //   permlane32_swap(R,T) -> U=[R@0,R@1,T@0,T@1], W=[R@2,R@3,T@2,T@3]
    //   permlane16_swap(U,W) -> X=[R@0,R@2,T@0,T@2], Y=[R@1,R@3,T@1,T@3]
    // pa words: {X_h0, X_h1, Y_h0, Y_h1} = s pairs (8q..), verified mapping.
    bf16x8 pa[2];
#pragma unroll
    for (int nbq = 0; nbq < 2; ++nbq) {
      float e00 = __builtin_amdgcn_exp2f(sacc[nbq][0][0]);
      float e01 = __builtin_amdgcn_exp2f(sacc[nbq][0][1]);
      float e02 = __builtin_amdgcn_exp2f(sacc[nbq][0][2]);
      float e03 = __builtin_amdgcn_exp2f(sacc[nbq][0][3]);
      float e10 = __builtin_amdgcn_exp2f(sacc[nbq][1][0]);
      float e11 = __builtin_amdgcn_exp2f(sacc[nbq][1][1]);
      float e12 = __builtin_amdgcn_exp2f(sacc[nbq][1][2]);
      float e13 = __builtin_amdgcn_exp2f(sacc[nbq][1][3]);
      lsum_p[nbq] += ((e00 + e01) + (e02 + e03)) + ((e10 + e11) + (e12 + e13));
      unsigned int w00, w01, w10, w11;
      asm("v_cvt_pk_bf16_f32 %0, %1, %2" : "=v"(w00) : "v"(e00), "v"(e01));
      asm("v_cvt_pk_bf16_f32 %0, %1, %2" : "=v"(w01) : "v"(e02), "v"(e03));
      asm("v_cvt_pk_bf16_f32 %0, %1, %2" : "=v"(w10) : "v"(e10), "v"(e11));
      asm("v_cvt_pk_bf16_f32 %0, %1, %2" : "=v"(w11) : "v"(e12), "v"(e13));
      auto sa = __builtin_amdgcn_permlane32_swap(w00, w10, false, false);
      auto xa = __builtin_amdgcn_permlane16_swap(sa[0], sa[1], false, false);
      auto sb = __builtin_amdgcn_permlane32_swap(w01, w11, false, false);
      auto xb = __builtin_amdgcn_permlane16_swap(sb[0], sb[1], false, false);
      union { unsigned int u[4]; bf16x8 v; } pk_;
      pk_.u[0] = xa[0]; pk_.u[1] = xb[0]; pk_.u[2] = xa[1]; pk_.u[3] = xb[1];
      pa[nbq] = pk_.v;
    }

    // ---- PV(t): in-iteration (pa, vb all in registers) ----
    __builtin_amdgcn_s_setprio(1);
#pragma unroll
    for (int mbq = 0; mbq < 2; ++mbq)
#pragma unroll
      for (int nbd = 0; nbd < 4; ++nbd)
        oacc[mbq][nbd] = __builtin_amdgcn_mfma_f32_16x16x32_bf16(
            pa[mbq], vb[nbd], oacc[mbq][nbd], 0, 0, 0);
    __builtin_amdgcn_s_setprio(0);
  }

  // ---- lsum: cross-quad reduce ----
#pragma unroll
  for (int nbq = 0; nbq < 2; ++nbq) {
    lsum_p[nbq] += __shfl_xor(lsum_p[nbq], 16, 64);
    lsum_p[nbq] += __shfl_xor(lsum_p[nbq], 32, 64);
  }

  // ---- epilogue: 2-way s-merge through LDS (K/V buffers dead) ----
  __syncthreads();
  float* red_w = (float*)smem + wave * 2176;  // [32 q][68] floats, 8704B/wave
#pragma unroll
  for (int mbq = 0; mbq < 2; ++mbq)
#pragma unroll
    for (int nbd = 0; nbd < 4; ++nbd)
#pragma unroll
      for (int r = 0; r < 4; ++r)
        red_w[(mbq * 16 + quad * 4 + r) * 68 + nbd * 16 + l16] =
            oacc[mbq][nbd][r];
  float* ls = (float*)(smem + 34816);  // [4 waves][32 q]
  if (quad == 0) {
#pragma unroll
    for (int nbq = 0; nbq < 2; ++nbq)
      ls[wave * 32 + nbq * 16 + l16] = lsum_p[nbq];
  }
  __syncthreads();

  // wave w writes output rows [w*16, w*16+16): sources = waves {2*qh, 2*qh+1}
  const float* redA = (float*)smem + (2 * (wave >> 1)) * 2176;
  const float* redB = redA + 2176;
  const float* lsA  = ls + (wave >> 1) * 64;
#pragma unroll
  for (int p = 0; p < 4; ++p) {
    const int lr  = p * 4 + quad;            // 0..15 within this wave's rows
    const int q32 = (wave & 1) * 16 + lr;    // row within the q-half
    const int qo  = (wave >> 1) * 32 + q32;  // 0..63 within the q-tile
    const float lt = lsA[q32] + lsA[32 + q32];
    float4 a = *(const float4*)&redA[q32 * 68 + l16 * 4];
    float4 b = *(const float4*)&redB[q32 * 68 + l16 * 4];
    const float li = 1.f / lt;
    float4 o;
    o.x = (a.x + b.x) * li; o.y = (a.y + b.y) * li;
    o.z = (a.z + b.z) * li; o.w = (a.w + b.w) * li;
    *(float4*)&Og[(((size_t)n * L_ + l0 + qo) * H_ + h) * D_ + l16 * 4] = o;
  }
}

// ---------------------------------------------------------------------------
extern "C" void kernel_launch(void* const* d_in, const int* in_sizes, int n_in,
                              void* d_out, int out_size, void* d_ws, size_t ws_size,
                              hipStream_t stream) {
  const float* Q = (const float*)d_in[0];
  const float* K = (const float*)d_in[1];
  const float* V = (const float*)d_in[2];
  float* O = (float*)d_out;

  bf16_t* Kb  = (bf16_t*)d_ws;                   // [nh][s][d] bf16
  bf16_t* Vtb = Kb + (size_t)N_ * H_ * S_ * D_;  // [nh][d][s] bf16

  prep<<<dim3(S_ / 64, N_ * H_), 256, 0, stream>>>(K, V, Kb, Vtb);
  fattn<<<dim3(32 * 32, 1), 256, 0, stream>>>(Q, Kb, Vtb, O);
}

// Round 3
// 136.354 us; speedup vs baseline: 1.0872x; 1.0872x over previous
//
#include <hip/hip_runtime.h>
#include <hip/hip_bf16.h>
#include <math.h>

typedef __bf16 bf16_t;
typedef __bf16 bf16x2 __attribute__((ext_vector_type(2)));
typedef __bf16 bf16x4 __attribute__((ext_vector_type(4)));
typedef __bf16 bf16x8 __attribute__((ext_vector_type(8)));
typedef float floatx4 __attribute__((ext_vector_type(4)));

constexpr int N_ = 4, L_ = 2048, S_ = 2048, H_ = 8, D_ = 64;

// async global->LDS, 16B/lane; LDS dest = wave-uniform base + lane*16
__device__ __forceinline__ void async_load16(const void* g, void* l) {
  __builtin_amdgcn_global_load_lds(
      (const __attribute__((address_space(1))) void*)g,
      (__attribute__((address_space(3))) void*)l, 16, 0, 0);
}

// ---------------------------------------------------------------------------
// prologue: K fp32 [n,s,h,d] -> bf16 Kb [nh,s,d]; V fp32 -> bf16 Vtb [nh,d,s]
__global__ __launch_bounds__(256)
void prep(const float* __restrict__ Kg, const float* __restrict__ Vg,
          bf16_t* __restrict__ Kb, bf16_t* __restrict__ Vtb) {
  __shared__ bf16x2 pr_sh[64 * 33];
  const int tid = threadIdx.x;
  const int nh = blockIdx.y, s0 = blockIdx.x * 64;
  const int n = nh >> 3, h = nh & 7;
  {
    const int srow = tid >> 2, d0 = (tid & 3) * 16;
    const float* kp = Kg + (((size_t)n * S_ + s0 + srow) * H_ + h) * D_ + d0;
    float4 x0 = ((const float4*)kp)[0], x1 = ((const float4*)kp)[1];
    float4 x2 = ((const float4*)kp)[2], x3 = ((const float4*)kp)[3];
    bf16x8 f0, f1;
    f0[0] = (bf16_t)x0.x; f0[1] = (bf16_t)x0.y; f0[2] = (bf16_t)x0.z; f0[3] = (bf16_t)x0.w;
    f0[4] = (bf16_t)x1.x; f0[5] = (bf16_t)x1.y; f0[6] = (bf16_t)x1.z; f0[7] = (bf16_t)x1.w;
    f1[0] = (bf16_t)x2.x; f1[1] = (bf16_t)x2.y; f1[2] = (bf16_t)x2.z; f1[3] = (bf16_t)x2.w;
    f1[4] = (bf16_t)x3.x; f1[5] = (bf16_t)x3.y; f1[6] = (bf16_t)x3.z; f1[7] = (bf16_t)x3.w;
    *(bf16x8*)&Kb[((size_t)nh * S_ + s0 + srow) * D_ + d0] = f0;
    *(bf16x8*)&Kb[((size_t)nh * S_ + s0 + srow) * D_ + d0 + 8] = f1;
  }
  {
    const int s2 = tid >> 3;
    const int dg = (tid & 7) * 8;
    const float* vp0 = Vg + (((size_t)n * S_ + s0 + 2 * s2) * H_ + h) * D_ + dg;
    const float* vp1 = vp0 + (size_t)H_ * D_;
    float4 a0 = ((const float4*)vp0)[0], a1 = ((const float4*)vp0)[1];
    float4 b0 = ((const float4*)vp1)[0], b1 = ((const float4*)vp1)[1];
    float r0[8] = { a0.x, a0.y, a0.z, a0.w, a1.x, a1.y, a1.z, a1.w };
    float r1[8] = { b0.x, b0.y, b0.z, b0.w, b1.x, b1.y, b1.z, b1.w };
#pragma unroll
    for (int j = 0; j < 8; ++j) {
      bf16x2 pr; pr[0] = (bf16_t)r0[j]; pr[1] = (bf16_t)r1[j];
      pr_sh[(dg + j) * 33 + s2] = pr;
    }
  }
  __syncthreads();
  {
    const int dr = tid >> 2, sq = tid & 3;
    bf16x8 o0, o1;
#pragma unroll
    for (int p = 0; p < 4; ++p) {
      bf16x2 v = pr_sh[dr * 33 + sq * 8 + p];
      o0[2 * p] = v[0]; o0[2 * p + 1] = v[1];
    }
#pragma unroll
    for (int p = 0; p < 4; ++p) {
      bf16x2 v = pr_sh[dr * 33 + sq * 8 + 4 + p];
      o1[2 * p] = v[0]; o1[2 * p + 1] = v[1];
    }
    bf16_t* op = &Vtb[((size_t)nh * D_ + dr) * S_ + s0 + sq * 16];
    *(bf16x8*)op = o0;
    *(bf16x8*)(op + 8) = o1;
  }
}

// ---------------------------------------------------------------------------
// fattn r12: shared-K/V restructure. Block = 512 thr / 8 waves, q-tile 128;
// wave owns 16 q rows x all d, iterates ALL s in 32 shared chunks of 64.
// L2 traffic halves (256MB: each block reads K/V once for 128 q instead of
// per-64q), DMA issue drops to 2 loads/wave/iter. Triple-buffered shared
// chunks (48KB), ONE raw s_barrier per iter + counted vmcnt(2): staged
// loads stay in flight a full iteration; no steady-state drain. Raw
// s_barrier (NOT __syncthreads: that would vmcnt(0)-drain the prefetch).
// In-register softmax (cvt_pk + permlane, verified r11). Epilogue: no
// cross-wave merge needed (wave owns complete rows) -> direct store.
__global__ __launch_bounds__(512, 4)
void fattn(const float* __restrict__ Qg, const bf16_t* __restrict__ Kb,
           const bf16_t* __restrict__ Vtb, float* __restrict__ Og) {
  __shared__ __align__(16) char smem[49152];  // 3 x (8KB K + 8KB V)

  const int tid  = threadIdx.x;
  const int wave = tid >> 6;
  const int lane = tid & 63;
  const int quad = lane >> 4;
  const int l16  = lane & 15;

  // XCD swizzle: lb&7 == nh&7 -> all 16 q-blocks of one nh on one XCD;
  // each XCD L2 holds 4 nh x 1MB = 4MB K/V (exactly fits).
  const int lb = blockIdx.x;
  const int nh = lb & 31;
  const int qb = lb >> 5;
  const int n  = nh >> 3;
  const int h  = nh & 7;
  const int qrow0 = qb * 128 + wave * 16;

  // ---- Q B-frags (B[k=d][n=q]: n=l16, k=quad*8+j), scale*log2e folded ----
  const float qs = 0.125f * 1.44269504088896340736f;
  bf16x8 qf[2];
#pragma unroll
  for (int kc = 0; kc < 2; ++kc) {
    const float* p = Qg + (((size_t)n * L_ + qrow0 + l16) * H_ + h) * D_ +
                     kc * 32 + quad * 8;
    float4 a = ((const float4*)p)[0];
    float4 b = ((const float4*)p)[1];
    bf16x8 f;
    f[0] = (bf16_t)(a.x * qs); f[1] = (bf16_t)(a.y * qs);
    f[2] = (bf16_t)(a.z * qs); f[3] = (bf16_t)(a.w * qs);
    f[4] = (bf16_t)(b.x * qs); f[5] = (bf16_t)(b.y * qs);
    f[6] = (bf16_t)(b.z * qs); f[7] = (bf16_t)(b.w * qs);
    qf[kc] = f;
  }

  floatx4 oacc[4];
#pragma unroll
  for (int b = 0; b < 4; ++b) oacc[b] = (floatx4){0.f, 0.f, 0.f, 0.f};
  float lsum = 0.f;

  const bf16_t* kbase = Kb + (size_t)nh * S_ * D_;
  const bf16_t* vbase = Vtb + (size_t)nh * D_ * S_;

  // DMA lane constants: row-in-group = lane>>3, XOR-swizzled 16B chunk.
  // LDS chunk c of row r holds global chunk c^(r&7) (row&7 == lane>>3).
  const int rr  = lane >> 3;
  const int cc8 = ((lane & 7) ^ (lane >> 3)) * 8;

  // prime chunks 0 -> buf0, 1 -> buf1 (2 loads per wave per chunk)
  {
    async_load16(kbase + (size_t)(0 * 64 + wave * 8 + rr) * 64 + cc8,
                 smem + 0 * 16384 + wave * 1024);
    async_load16(vbase + (size_t)(wave * 8 + rr) * S_ + 0 * 64 + cc8,
                 smem + 0 * 16384 + 8192 + wave * 1024);
    async_load16(kbase + (size_t)(1 * 64 + wave * 8 + rr) * 64 + cc8,
                 smem + 1 * 16384 + wave * 1024);
    async_load16(vbase + (size_t)(wave * 8 + rr) * S_ + 1 * 64 + cc8,
                 smem + 1 * 16384 + 8192 + wave * 1024);
  }

  for (int t = 0; t < 32; ++t) {
    const int j = t % 3;
    // own chunk-t loads done (t+1's 2 may stay in flight); barrier => all
    // waves' chunk-t loads landed AND everyone finished reading buf[(t-1)%3]
    // (their frag reads drained before their t-1 MFMAs by data dependence).
    if (t < 31) asm volatile("s_waitcnt vmcnt(2)" ::: "memory");
    else        asm volatile("s_waitcnt vmcnt(0)" ::: "memory");
    __builtin_amdgcn_s_barrier();
    // stage chunk t+2 into buf[(t+2)%3] (= chunk t-1's buffer, now free);
    // issued before compute -> a full iteration of flight time.
    if (t < 30) {
      const int jn = (t + 2) % 3;
      async_load16(kbase + (size_t)((t + 2) * 64 + wave * 8 + rr) * 64 + cc8,
                   smem + jn * 16384 + wave * 1024);
      async_load16(vbase + (size_t)(wave * 8 + rr) * S_ + (t + 2) * 64 + cc8,
                   smem + jn * 16384 + 8192 + wave * 1024);
    }

    const bf16_t* kbufj = (const bf16_t*)(smem + j * 16384);
    const bf16_t* vbufj = (const bf16_t*)(smem + j * 16384 + 8192);

    // ---- S^T(t) = K Q^T over 64 s (4 m-blocks), per-mb reads limit regs ----
    floatx4 sacc[4];
    __builtin_amdgcn_s_setprio(1);
#pragma unroll
    for (int mb = 0; mb < 4; ++mb) {
      bf16x8 ka0 = *(const bf16x8*)
          &kbufj[(mb * 16 + l16) * 64 + (((0 * 4 + quad) ^ (l16 & 7)) * 8)];
      bf16x8 ka1 = *(const bf16x8*)
          &kbufj[(mb * 16 + l16) * 64 + (((1 * 4 + quad) ^ (l16 & 7)) * 8)];
      floatx4 acc = (floatx4){0.f, 0.f, 0.f, 0.f};
      acc = __builtin_amdgcn_mfma_f32_16x16x32_bf16(ka0, qf[0], acc, 0, 0, 0);
      acc = __builtin_amdgcn_mfma_f32_16x16x32_bf16(ka1, qf[1], acc, 0, 0, 0);
      sacc[mb] = acc;
    }
    __builtin_amdgcn_s_setprio(0);

    // ---- exp2 + cvt_pk + permlane -> PV A-frags (verified r11 mapping) ----
    // pair p from (sacc[2p], sacc[2p+1]) covers s-local 32p..32p+31.
    bf16x8 pa[2];
#pragma unroll
    for (int p = 0; p < 2; ++p) {
      float e00 = __builtin_amdgcn_exp2f(sacc[2 * p][0]);
      float e01 = __builtin_amdgcn_exp2f(sacc[2 * p][1]);
      float e02 = __builtin_amdgcn_exp2f(sacc[2 * p][2]);
      float e03 = __builtin_amdgcn_exp2f(sacc[2 * p][3]);
      float e10 = __builtin_amdgcn_exp2f(sacc[2 * p + 1][0]);
      float e11 = __builtin_amdgcn_exp2f(sacc[2 * p + 1][1]);
      float e12 = __builtin_amdgcn_exp2f(sacc[2 * p + 1][2]);
      float e13 = __builtin_amdgcn_exp2f(sacc[2 * p + 1][3]);
      lsum += ((e00 + e01) + (e02 + e03)) + ((e10 + e11) + (e12 + e13));
      unsigned int w00, w01, w10, w11;
      asm("v_cvt_pk_bf16_f32 %0, %1, %2" : "=v"(w00) : "v"(e00), "v"(e01));
      asm("v_cvt_pk_bf16_f32 %0, %1, %2" : "=v"(w01) : "v"(e02), "v"(e03));
      asm("v_cvt_pk_bf16_f32 %0, %1, %2" : "=v"(w10) : "v"(e10), "v"(e11));
      asm("v_cvt_pk_bf16_f32 %0, %1, %2" : "=v"(w11) : "v"(e12), "v"(e13));
      auto sa = __builtin_amdgcn_permlane32_swap(w00, w10, false, false);
      auto xa = __builtin_amdgcn_permlane16_swap(sa[0], sa[1], false, false);
      auto sb = __builtin_amdgcn_permlane32_swap(w01, w11, false, false);
      auto xb = __builtin_amdgcn_permlane16_swap(sb[0], sb[1], false, false);
      union { unsigned int u[4]; bf16x8 v; } pk_;
      pk_.u[0] = xa[0]; pk_.u[1] = xb[0]; pk_.u[2] = xa[1]; pk_.u[3] = xb[1];
      pa[p] = pk_.v;
    }

    // ---- PV(t): vb frags read per-nbd (B[k=s: quad*8+j][n=d: l16]) ----
    __builtin_amdgcn_s_setprio(1);
#pragma unroll
    for (int nbd = 0; nbd < 4; ++nbd) {
      bf16x8 vb0 = *(const bf16x8*)
          &vbufj[(nbd * 16 + l16) * 64 + (((0 * 4 + quad) ^ (l16 & 7)) * 8)];
      bf16x8 vb1 = *(const bf16x8*)
          &vbufj[(nbd * 16 + l16) * 64 + (((1 * 4 + quad) ^ (l16 & 7)) * 8)];
      oacc[nbd] = __builtin_amdgcn_mfma_f32_16x16x32_bf16(pa[0], vb0, oacc[nbd], 0, 0, 0);
      oacc[nbd] = __builtin_amdgcn_mfma_f32_16x16x32_bf16(pa[1], vb1, oacc[nbd], 0, 0, 0);
    }
    __builtin_amdgcn_s_setprio(0);
  }

  // ---- epilogue: wave-local. lsum: reduce across quads, then per-row bcast.
  lsum += __shfl_xor(lsum, 16, 64);
  lsum += __shfl_xor(lsum, 32, 64);
  float li[4];
#pragma unroll
  for (int r = 0; r < 4; ++r)
    li[r] = 1.f / __shfl(lsum, quad * 4 + r, 64);

  // oacc layout: lane(l16,quad) reg r = O[q = qrow0+quad*4+r][d = nbd*16+l16]
#pragma unroll
  for (int nbd = 0; nbd < 4; ++nbd)
#pragma unroll
    for (int r = 0; r < 4; ++r)
      Og[(((size_t)n * L_ + qrow0 + quad * 4 + r) * H_ + h) * D_ +
         nbd * 16 + l16] = oacc[nbd][r] * li[r];
}

// ---------------------------------------------------------------------------
extern "C" void kernel_launch(void* const* d_in, const int* in_sizes, int n_in,
                              void* d_out, int out_size, void* d_ws, size_t ws_size,
                              hipStream_t stream) {
  const float* Q = (const float*)d_in[0];
  const float* K = (const float*)d_in[1];
  const float* V = (const float*)d_in[2];
  float* O = (float*)d_out;

  bf16_t* Kb  = (bf16_t*)d_ws;                   // [nh][s][d] bf16
  bf16_t* Vtb = Kb + (size_t)N_ * H_ * S_ * D_;  // [nh][d][s] bf16

  prep<<<dim3(S_ / 64, N_ * H_), 256, 0, stream>>>(K, V, Kb, Vtb);
  fattn<<<dim3(512, 1), 512, 0, stream>>>(Q, Kb, Vtb, O);
}

// Round 4
// 134.073 us; speedup vs baseline: 1.1057x; 1.0170x over previous
//
#include <hip/hip_runtime.h>
#include <hip/hip_bf16.h>
#include <math.h>

typedef __bf16 bf16_t;
typedef __bf16 bf16x2 __attribute__((ext_vector_type(2)));
typedef __bf16 bf16x4 __attribute__((ext_vector_type(4)));
typedef __bf16 bf16x8 __attribute__((ext_vector_type(8)));
typedef float floatx4 __attribute__((ext_vector_type(4)));

constexpr int N_ = 4, L_ = 2048, S_ = 2048, H_ = 8, D_ = 64;

// async global->LDS, 16B/lane; LDS dest = wave-uniform base + lane*16
__device__ __forceinline__ void async_load16(const void* g, void* l) {
  __builtin_amdgcn_global_load_lds(
      (const __attribute__((address_space(1))) void*)g,
      (__attribute__((address_space(3))) void*)l, 16, 0, 0);
}

// ---------------------------------------------------------------------------
// prologue: K fp32 [n,s,h,d] -> bf16 Kb [nh,s,d]; V fp32 -> bf16 Vtb [nh,d,s]
__global__ __launch_bounds__(256)
void prep(const float* __restrict__ Kg, const float* __restrict__ Vg,
          bf16_t* __restrict__ Kb, bf16_t* __restrict__ Vtb) {
  __shared__ bf16x2 pr_sh[64 * 33];
  const int tid = threadIdx.x;
  const int nh = blockIdx.y, s0 = blockIdx.x * 64;
  const int n = nh >> 3, h = nh & 7;
  {
    const int srow = tid >> 2, d0 = (tid & 3) * 16;
    const float* kp = Kg + (((size_t)n * S_ + s0 + srow) * H_ + h) * D_ + d0;
    float4 x0 = ((const float4*)kp)[0], x1 = ((const float4*)kp)[1];
    float4 x2 = ((const float4*)kp)[2], x3 = ((const float4*)kp)[3];
    bf16x8 f0, f1;
    f0[0] = (bf16_t)x0.x; f0[1] = (bf16_t)x0.y; f0[2] = (bf16_t)x0.z; f0[3] = (bf16_t)x0.w;
    f0[4] = (bf16_t)x1.x; f0[5] = (bf16_t)x1.y; f0[6] = (bf16_t)x1.z; f0[7] = (bf16_t)x1.w;
    f1[0] = (bf16_t)x2.x; f1[1] = (bf16_t)x2.y; f1[2] = (bf16_t)x2.z; f1[3] = (bf16_t)x2.w;
    f1[4] = (bf16_t)x3.x; f1[5] = (bf16_t)x3.y; f1[6] = (bf16_t)x3.z; f1[7] = (bf16_t)x3.w;
    *(bf16x8*)&Kb[((size_t)nh * S_ + s0 + srow) * D_ + d0] = f0;
    *(bf16x8*)&Kb[((size_t)nh * S_ + s0 + srow) * D_ + d0 + 8] = f1;
  }
  {
    const int s2 = tid >> 3;
    const int dg = (tid & 7) * 8;
    const float* vp0 = Vg + (((size_t)n * S_ + s0 + 2 * s2) * H_ + h) * D_ + dg;
    const float* vp1 = vp0 + (size_t)H_ * D_;
    float4 a0 = ((const float4*)vp0)[0], a1 = ((const float4*)vp0)[1];
    float4 b0 = ((const float4*)vp1)[0], b1 = ((const float4*)vp1)[1];
    float r0[8] = { a0.x, a0.y, a0.z, a0.w, a1.x, a1.y, a1.z, a1.w };
    float r1[8] = { b0.x, b0.y, b0.z, b0.w, b1.x, b1.y, b1.z, b1.w };
#pragma unroll
    for (int j = 0; j < 8; ++j) {
      bf16x2 pr; pr[0] = (bf16_t)r0[j]; pr[1] = (bf16_t)r1[j];
      pr_sh[(dg + j) * 33 + s2] = pr;
    }
  }
  __syncthreads();
  {
    const int dr = tid >> 2, sq = tid & 3;
    bf16x8 o0, o1;
#pragma unroll
    for (int p = 0; p < 4; ++p) {
      bf16x2 v = pr_sh[dr * 33 + sq * 8 + p];
      o0[2 * p] = v[0]; o0[2 * p + 1] = v[1];
    }
#pragma unroll
    for (int p = 0; p < 4; ++p) {
      bf16x2 v = pr_sh[dr * 33 + sq * 8 + 4 + p];
      o1[2 * p] = v[0]; o1[2 * p + 1] = v[1];
    }
    bf16_t* op = &Vtb[((size_t)nh * D_ + dr) * S_ + s0 + sq * 16];
    *(bf16x8*)op = o0;
    *(bf16x8*)(op + 8) = o1;
  }
}

// ---------------------------------------------------------------------------
// fattn r13: phase-doubling. Same shared-K/V structure as r12 (512 thr,
// q-tile 128, wave = 16 q x all s) but 2 chunks (128 s) per barrier phase:
// 16 barriers instead of 32 -> waves spend 2x longer in independent code
// between lockstep points, so the LDS-burst / VALU-burst phase alignment
// that capped r12 at 27% MfmaUtil decorrelates. Pair-double-buffered LDS
// (2 x 32KB, 2 blocks/CU unchanged). Discipline per phase (proven r12):
// vmcnt(0) [own 4 loads, issued a full phase ago -> free] -> s_barrier ->
// stage next pair -> compute c0, c1. V-frag reads hoisted BEFORE the
// exp2/cvt/permlane chain so they overlap VALU. lsum split into 2 chains.
__global__ __launch_bounds__(512, 4)
void fattn(const float* __restrict__ Qg, const bf16_t* __restrict__ Kb,
           const bf16_t* __restrict__ Vtb, float* __restrict__ Og) {
  __shared__ __align__(16) char smem[65536];  // 2 pairs x (2 x (8KB K+8KB V))

  const int tid  = threadIdx.x;
  const int wave = tid >> 6;
  const int lane = tid & 63;
  const int quad = lane >> 4;
  const int l16  = lane & 15;

  // XCD swizzle: lb&7 == nh&7 -> all 16 q-blocks of one nh on one XCD;
  // each XCD L2 holds 4 nh x 1MB = 4MB K/V (exactly fits).
  const int lb = blockIdx.x;
  const int nh = lb & 31;
  const int qb = lb >> 5;
  const int n  = nh >> 3;
  const int h  = nh & 7;
  const int qrow0 = qb * 128 + wave * 16;

  // ---- Q B-frags (B[k=d][n=q]: n=l16, k=quad*8+j), scale*log2e folded ----
  const float qs = 0.125f * 1.44269504088896340736f;
  bf16x8 qf[2];
#pragma unroll
  for (int kc = 0; kc < 2; ++kc) {
    const float* p = Qg + (((size_t)n * L_ + qrow0 + l16) * H_ + h) * D_ +
                     kc * 32 + quad * 8;
    float4 a = ((const float4*)p)[0];
    float4 b = ((const float4*)p)[1];
    bf16x8 f;
    f[0] = (bf16_t)(a.x * qs); f[1] = (bf16_t)(a.y * qs);
    f[2] = (bf16_t)(a.z * qs); f[3] = (bf16_t)(a.w * qs);
    f[4] = (bf16_t)(b.x * qs); f[5] = (bf16_t)(b.y * qs);
    f[6] = (bf16_t)(b.z * qs); f[7] = (bf16_t)(b.w * qs);
    qf[kc] = f;
  }

  floatx4 oacc[4];
#pragma unroll
  for (int b = 0; b < 4; ++b) oacc[b] = (floatx4){0.f, 0.f, 0.f, 0.f};
  float lsum0 = 0.f, lsum1 = 0.f;

  const bf16_t* kbase = Kb + (size_t)nh * S_ * D_;
  const bf16_t* vbase = Vtb + (size_t)nh * D_ * S_;

  // DMA lane constants: row-in-group = lane>>3, XOR-swizzled 16B chunk.
  const int rr  = lane >> 3;
  const int cc8 = ((lane & 7) ^ (lane >> 3)) * 8;

  // prime pair 0 with chunks {0, 64} (4 loads per wave)
  {
    async_load16(kbase + (size_t)(0 + wave * 8 + rr) * 64 + cc8,
                 smem + wave * 1024);
    async_load16(vbase + (size_t)(wave * 8 + rr) * S_ + 0 + cc8,
                 smem + 8192 + wave * 1024);
    async_load16(kbase + (size_t)(64 + wave * 8 + rr) * 64 + cc8,
                 smem + 16384 + wave * 1024);
    async_load16(vbase + (size_t)(wave * 8 + rr) * S_ + 64 + cc8,
                 smem + 24576 + wave * 1024);
  }

  for (int p = 0; p < 16; ++p) {
    char* cur = smem + (p & 1) * 32768;
    // own 4 loads for this pair (issued during phase p-1) -> effectively
    // landed long ago; then barrier => ALL waves' loads for this pair done
    // AND everyone finished reading the other pair (phase p-1's data).
    asm volatile("s_waitcnt vmcnt(0)" ::: "memory");
    __builtin_amdgcn_s_barrier();
    if (p < 15) {
      char* nxt = smem + ((p + 1) & 1) * 32768;
      const int s0 = (p + 1) * 128;
      async_load16(kbase + (size_t)(s0 + wave * 8 + rr) * 64 + cc8,
                   nxt + wave * 1024);
      async_load16(vbase + (size_t)(wave * 8 + rr) * S_ + s0 + cc8,
                   nxt + 8192 + wave * 1024);
      async_load16(kbase + (size_t)(s0 + 64 + wave * 8 + rr) * 64 + cc8,
                   nxt + 16384 + wave * 1024);
      async_load16(vbase + (size_t)(wave * 8 + rr) * S_ + s0 + 64 + cc8,
                   nxt + 24576 + wave * 1024);
    }

#pragma unroll
    for (int c = 0; c < 2; ++c) {
      const bf16_t* kbufj = (const bf16_t*)(cur + c * 16384);
      const bf16_t* vbufj = (const bf16_t*)(cur + c * 16384 + 8192);

      // ---- S^T = K Q^T over 64 s (4 m-blocks) ----
      floatx4 sacc[4];
      __builtin_amdgcn_s_setprio(1);
#pragma unroll
      for (int mb = 0; mb < 4; ++mb) {
        bf16x8 ka0 = *(const bf16x8*)
            &kbufj[(mb * 16 + l16) * 64 + ((quad ^ (l16 & 7)) * 8)];
        bf16x8 ka1 = *(const bf16x8*)
            &kbufj[(mb * 16 + l16) * 64 + (((4 + quad) ^ (l16 & 7)) * 8)];
        floatx4 acc = (floatx4){0.f, 0.f, 0.f, 0.f};
        acc = __builtin_amdgcn_mfma_f32_16x16x32_bf16(ka0, qf[0], acc, 0, 0, 0);
        acc = __builtin_amdgcn_mfma_f32_16x16x32_bf16(ka1, qf[1], acc, 0, 0, 0);
        sacc[mb] = acc;
      }
      __builtin_amdgcn_s_setprio(0);

      // ---- V-frag reads hoisted: overlap the exp2/cvt/permlane chain ----
      bf16x8 vbf[4][2];
#pragma unroll
      for (int nbd = 0; nbd < 4; ++nbd) {
        vbf[nbd][0] = *(const bf16x8*)
            &vbufj[(nbd * 16 + l16) * 64 + ((quad ^ (l16 & 7)) * 8)];
        vbf[nbd][1] = *(const bf16x8*)
            &vbufj[(nbd * 16 + l16) * 64 + (((4 + quad) ^ (l16 & 7)) * 8)];
      }

      // ---- exp2 + cvt_pk + permlane -> PV A-frags (verified r11 mapping) ----
      bf16x8 pa[2];
#pragma unroll
      for (int pp = 0; pp < 2; ++pp) {
        float e00 = __builtin_amdgcn_exp2f(sacc[2 * pp][0]);
        float e01 = __builtin_amdgcn_exp2f(sacc[2 * pp][1]);
        float e02 = __builtin_amdgcn_exp2f(sacc[2 * pp][2]);
        float e03 = __builtin_amdgcn_exp2f(sacc[2 * pp][3]);
        float e10 = __builtin_amdgcn_exp2f(sacc[2 * pp + 1][0]);
        float e11 = __builtin_amdgcn_exp2f(sacc[2 * pp + 1][1]);
        float e12 = __builtin_amdgcn_exp2f(sacc[2 * pp + 1][2]);
        float e13 = __builtin_amdgcn_exp2f(sacc[2 * pp + 1][3]);
        if (pp == 0) lsum0 += ((e00 + e01) + (e02 + e03)) + ((e10 + e11) + (e12 + e13));
        else         lsum1 += ((e00 + e01) + (e02 + e03)) + ((e10 + e11) + (e12 + e13));
        unsigned int w00, w01, w10, w11;
        asm("v_cvt_pk_bf16_f32 %0, %1, %2" : "=v"(w00) : "v"(e00), "v"(e01));
        asm("v_cvt_pk_bf16_f32 %0, %1, %2" : "=v"(w01) : "v"(e02), "v"(e03));
        asm("v_cvt_pk_bf16_f32 %0, %1, %2" : "=v"(w10) : "v"(e10), "v"(e11));
        asm("v_cvt_pk_bf16_f32 %0, %1, %2" : "=v"(w11) : "v"(e12), "v"(e13));
        auto sa = __builtin_amdgcn_permlane32_swap(w00, w10, false, false);
        auto xa = __builtin_amdgcn_permlane16_swap(sa[0], sa[1], false, false);
        auto sb = __builtin_amdgcn_permlane32_swap(w01, w11, false, false);
        auto xb = __builtin_amdgcn_permlane16_swap(sb[0], sb[1], false, false);
        union { unsigned int u[4]; bf16x8 v; } pk_;
        pk_.u[0] = xa[0]; pk_.u[1] = xb[0]; pk_.u[2] = xa[1]; pk_.u[3] = xb[1];
        pa[pp] = pk_.v;
      }

      // ---- PV: frags already in registers ----
      __builtin_amdgcn_s_setprio(1);
#pragma unroll
      for (int nbd = 0; nbd < 4; ++nbd) {
        oacc[nbd] = __builtin_amdgcn_mfma_f32_16x16x32_bf16(
            pa[0], vbf[nbd][0], oacc[nbd], 0, 0, 0);
        oacc[nbd] = __builtin_amdgcn_mfma_f32_16x16x32_bf16(
            pa[1], vbf[nbd][1], oacc[nbd], 0, 0, 0);
      }
      __builtin_amdgcn_s_setprio(0);
    }
  }

  // ---- epilogue: wave-local. lsum: reduce across quads, then per-row bcast.
  float lsum = lsum0 + lsum1;
  lsum += __shfl_xor(lsum, 16, 64);
  lsum += __shfl_xor(lsum, 32, 64);
  float li[4];
#pragma unroll
  for (int r = 0; r < 4; ++r)
    li[r] = 1.f / __shfl(lsum, quad * 4 + r, 64);

  // oacc layout: lane(l16,quad) reg r = O[q = qrow0+quad*4+r][d = nbd*16+l16]
#pragma unroll
  for (int nbd = 0; nbd < 4; ++nbd)
#pragma unroll
    for (int r = 0; r < 4; ++r)
      Og[(((size_t)n * L_ + qrow0 + quad * 4 + r) * H_ + h) * D_ +
         nbd * 16 + l16] = oacc[nbd][r] * li[r];
}

// ---------------------------------------------------------------------------
extern "C" void kernel_launch(void* const* d_in, const int* in_sizes, int n_in,
                              void* d_out, int out_size, void* d_ws, size_t ws_size,
                              hipStream_t stream) {
  const float* Q = (const float*)d_in[0];
  const float* K = (const float*)d_in[1];
  const float* V = (const float*)d_in[2];
  float* O = (float*)d_out;

  bf16_t* Kb  = (bf16_t*)d_ws;                   // [nh][s][d] bf16
  bf16_t* Vtb = Kb + (size_t)N_ * H_ * S_ * D_;  // [nh][d][s] bf16

  prep<<<dim3(S_ / 64, N_ * H_), 256, 0, stream>>>(K, V, Kb, Vtb);
  fattn<<<dim3(512, 1), 512, 0, stream>>>(Q, Kb, Vtb, O);
}